// Round 3
// baseline (34635.165 us; speedup 1.0000x reference)
//
#include <hip/hip_runtime.h>
#include <math.h>
#include <stdint.h>

#define BBOX_CLAMP 4.135166556742356f
#define SQH 0.70710678118654752f
#define SQ2 1.41421356237309515f

__device__ __forceinline__ unsigned okey(float f){
  unsigned u = __float_as_uint(f);
  return (u & 0x80000000u) ? ~u : (u | 0x80000000u);
}

// ---------------- one-time weight transpose: wT[(cin*9+k)*256 + co] ----------------
__global__ void k_wtrans(const float* __restrict__ w, float* __restrict__ wT){
  const int ck = blockIdx.x;      // cin*9+k  (0..2303)
  const int co = threadIdx.x;     // 0..255
  wT[ck*256 + co] = w[co*2304 + ck];
}

// row-stationary conv update: row r of the (TH+2)x12 tile contributes to
// output rows py in [r-2, r] with kh = r-py. Per output element the fmaf
// chain order stays cin -> kh -> kw (bit-identical to previous passing runs).
template<int TH>
__device__ __forceinline__ void conv_rows(const float (*tile)[12], const float* wr, float* acc){
#pragma unroll
  for (int r=0; r<TH+2; ++r){
    const float4 q0 = *reinterpret_cast<const float4*>(&tile[r][0]);
    const float4 q1 = *reinterpret_cast<const float4*>(&tile[r][4]);
    const float4 q2 = *reinterpret_cast<const float4*>(&tile[r][8]);
    float rw[12];
    rw[0]=q0.x; rw[1]=q0.y; rw[2]=q0.z; rw[3]=q0.w;
    rw[4]=q1.x; rw[5]=q1.y; rw[6]=q1.z; rw[7]=q1.w;
    rw[8]=q2.x; rw[9]=q2.y; rw[10]=q2.z; rw[11]=q2.w;
    const int py0 = (r>=2) ? (r-2) : 0;
    const int py1 = (r<=TH-1) ? r : (TH-1);
#pragma unroll
    for (int py=py0; py<=py1; ++py){
      const int kh = r - py;
#pragma unroll
      for (int px=0; px<8; ++px){
        float s = acc[py*8+px];
        s = fmaf(rw[px+0], wr[kh*3+0], s);
        s = fmaf(rw[px+1], wr[kh*3+1], s);
        s = fmaf(rw[px+2], wr[kh*3+2], s);
        acc[py*8+px] = s;
      }
    }
  }
}

// ---------------- fused stem conv3x3+bias+relu + obj/box 1x1 heads ----------------
template<int TH>
__global__ __launch_bounds__(256, 4) void k_stem(
    const float* __restrict__ feat,   // [8][256][H][W]
    const float* __restrict__ wT,     // [2304][256]
    const float* __restrict__ bstem,  // [256]
    const float* __restrict__ wobj,   // [3][256]
    const float* __restrict__ bobj,   // [3]
    const float* __restrict__ wbox,   // [12][256]
    const float* __restrict__ bbox,   // [12]
    float* __restrict__ scores,       // [8][H*W*3]
    float* __restrict__ deltas,       // [8][H*W*12]
    const int H, const int W)
{
  __shared__ __align__(16) float in_t[2][TH+2][12];
  __shared__ float x_lds[32][257];

  const int tx0 = blockIdx.x*8, ty0 = blockIdx.y*TH;
  const int b = blockIdx.z;
  const int co = threadIdx.x;
  const size_t HW = (size_t)H*W;
  const float* fb = feat + (size_t)b*256*HW;

  constexpr int LC = (TH+2)*10;
  const int lty = co/10, ltx = co - lty*10;
  const bool lactive = (co < LC);
  const int gy = ty0-1+lty, gx = tx0-1+ltx;
  const bool inb = lactive && (gy>=0 && gy<H && gx>=0 && gx<W);
  const float* gsrc = fb + ((size_t)(inb?gy:0)*W + (size_t)(inb?gx:0));

  float acc[TH*8];
#pragma unroll
  for (int i=0;i<TH*8;++i) acc[i]=0.f;

  // preload cin 0 tile + weights
  if (lactive) in_t[0][lty][ltx] = inb ? *gsrc : 0.f;
  float wa[9], wb[9];
#pragma unroll
  for (int k=0;k<9;++k) wa[k] = wT[k*256+co];
  __syncthreads();

  for (int it=0; it<128; ++it){
    const int cinB = 2*it+1;
    // prefetch cinB (tile value -> reg, weights -> wb) before computing cinB-1
    float pv = 0.f;
    if (inb) pv = gsrc[(size_t)cinB*HW];
#pragma unroll
    for (int k=0;k<9;++k) wb[k] = wT[((size_t)cinB*9+(size_t)k)*256+co];

    conv_rows<TH>(in_t[0], wa, acc);

    if (lactive) in_t[1][lty][ltx] = pv;   // write-late (T14)
    __syncthreads();

    // prefetch cinB+1 into (pv, wa) before computing cinB
    pv = 0.f;
    if (it < 127){
      if (inb) pv = gsrc[(size_t)(cinB+1)*HW];
#pragma unroll
      for (int k=0;k<9;++k) wa[k] = wT[((size_t)(cinB+1)*9+(size_t)k)*256+co];
    }

    conv_rows<TH>(in_t[1], wb, acc);

    if (it < 127 && lactive) in_t[0][lty][ltx] = pv;
    __syncthreads();
  }

  // bias + relu
  const float bs = bstem[co];
#pragma unroll
  for (int i=0;i<TH*8;++i) acc[i] = fmaxf(acc[i]+bs, 0.f);

  // heads: halves of 32 pixels through LDS
  const int p_loc = co & 31;
  const int g = co >> 5;                 // 0..7
  const int oc0 = g*2, oc1 = g*2+1;      // oc in [0,16), 15 unused
  const float* wh0 = (oc0<3) ? (wobj + oc0*256) : (wbox + (oc0-3)*256);
  const float* wh1 = (oc1<3) ? (wobj + oc1*256) : ((oc1<15) ? (wbox + (oc1-3)*256) : wbox);
  const float bias0 = (oc0<3) ? bobj[oc0] : bbox[oc0-3];
  const float bias1 = (oc1<3) ? bobj[oc1] : ((oc1<15) ? bbox[oc1-3] : 0.f);

  constexpr int NH = (TH*8)/32;
#pragma unroll
  for (int half=0; half<NH; ++half){
    __syncthreads();
#pragma unroll
    for (int i=0;i<32;++i) x_lds[i][co] = acc[half*32 + i];
    __syncthreads();
    const int p  = half*32 + p_loc;
    const int py = p>>3, px = p&7;
    const int hh = ty0+py, ww = tx0+px;
    const size_t loc = (size_t)hh*W + ww;
    float s0 = 0.f, s1 = 0.f;
#pragma unroll 8
    for (int c=0;c<256;++c){
      const float xv = x_lds[p_loc][c];
      s0 = fmaf(xv, wh0[c], s0);
      s1 = fmaf(xv, wh1[c], s1);
    }
    s0 += bias0; s1 += bias1;
    if (oc0 < 3) scores[b*HW*3 + loc*3 + oc0] = s0;
    else         deltas[b*HW*12 + loc*12 + (oc0-3)] = s0;
    if (oc1 < 3) scores[b*HW*3 + loc*3 + oc1] = s1;
    else if (oc1 < 15) deltas[b*HW*12 + loc*12 + (oc1-3)] = s1;
  }
}

// ---------------- per (level,image): top-400 -> decode -> NMS -> top-50 ----------------
__global__ __launch_bounds__(1024) void k_select(
    const float* __restrict__ sc3, const float* __restrict__ sc4, const float* __restrict__ sc5,
    const float* __restrict__ dl3, const float* __restrict__ dl4, const float* __restrict__ dl5,
    float* __restrict__ out)
{
  const int lvl = blockIdx.x >> 3;
  const int b   = blockIdx.x & 7;
  int N, W; float stride; const float* sc; const float* dl;
  if (lvl==0){ N=49152; W=128; stride=8.f;  sc=sc3; dl=dl3; }
  else if (lvl==1){ N=12288; W=64; stride=16.f; sc=sc4; dl=dl4; }
  else { N=3072; W=32; stride=32.f; sc=sc5; dl=dl5; }
  sc += (size_t)b*N;
  dl += (size_t)b*(size_t)(N/3)*12;

  __shared__ unsigned hist[256];
  __shared__ unsigned s_prefix;
  __shared__ int s_need;
  __shared__ int s_cntc;
  __shared__ unsigned long long cand[1024];
  __shared__ int tk[400];
  __shared__ float bx1[400], by1[400], bx2[400], by2[400], bar_[400];
  __shared__ unsigned long long mask[400][7];
  __shared__ int olist[50];

  const int t = threadIdx.x;

  // ---- radix-select: find key K of the 400th-largest score ----
  if (t==0){ s_prefix=0u; s_need=400; }
  for (int pass=0; pass<4; ++pass){
    const int shift = 24 - 8*pass;
    if (t<256) hist[t]=0u;
    __syncthreads();
    const unsigned pref = s_prefix;
    for (int i=t; i<N; i+=1024){
      const unsigned k = okey(sc[i]);
      if (pass==0 || (k >> (shift+8)) == pref)
        atomicAdd(&hist[(k>>shift)&255u], 1u);
    }
    __syncthreads();
    if (t==0){
      int need = s_need, cum=0, bsel=0;
      for (int bb=255; bb>=0; --bb){
        const int h = (int)hist[bb];
        if (cum + h >= need){ bsel=bb; break; }
        cum += h;
      }
      s_prefix = (pref<<8) | (unsigned)bsel;
      s_need = need - cum;
    }
    __syncthreads();
  }
  const unsigned K = s_prefix;

  // ---- compact candidates: all keys >= K (count >= 400 by construction) ----
  if (t==0) s_cntc = 0;
  cand[t] = 0ull;
  __syncthreads();
  for (int i=t; i<N; i+=1024){
    const unsigned k = okey(sc[i]);
    if (k >= K){
      const int pos = atomicAdd(&s_cntc, 1);
      if (pos < 1024)
        cand[pos] = ((unsigned long long)k<<32) | (unsigned long long)(0xFFFFFFFFu - (unsigned)i);
    }
  }
  __syncthreads();

  // ---- bitonic sort 1024 descending: (key desc, idx asc) ----
  for (int kk=2; kk<=1024; kk<<=1){
    for (int j=kk>>1; j>0; j>>=1){
      const int ixj = t ^ j;
      if (ixj > t){
        const unsigned long long a = cand[t], c = cand[ixj];
        const bool descending = ((t & kk) == 0);
        if ((a < c) == descending){ cand[t]=c; cand[ixj]=a; }
      }
      __syncthreads();
    }
  }

  // ---- decode top-400 boxes ----
  if (t < 400){
    const unsigned long long c = cand[t];
    const int gi = (int)(0xFFFFFFFFu - (unsigned)(c & 0xFFFFFFFFull));
    tk[t] = gi;
    const int loc = gi/3, a = gi - loc*3;
    const int hh = loc / W, ww = loc - hh*W;
    const float cx = (ww + 0.5f)*stride, cy = (hh + 0.5f)*stride;
    const float size = stride*8.f;
    const float sq = (a==0) ? SQH : ((a==1) ? 1.f : SQ2);
    const float hw_ = 0.5f*(size/sq);    // half width  (w = size/sqrt(r))
    const float hv_ = 0.5f*(size*sq);    // half height (h = size*sqrt(r))
    const float ax1 = cx - hw_, ax2 = cx + hw_;
    const float ay1 = cy - hv_, ay2 = cy + hv_;
    const float aw = ax2 - ax1, ah = ay2 - ay1;
    const float acx = ax1 + 0.5f*aw, acy = ay1 + 0.5f*ah;
    const float* dd = dl + (size_t)loc*12 + a*4;
    const float dx = dd[0], dy = dd[1];
    const float dw = fminf(fmaxf(dd[2], -BBOX_CLAMP), BBOX_CLAMP);
    const float dh = fminf(fmaxf(dd[3], -BBOX_CLAMP), BBOX_CLAMP);
    const float pcx = acx + dx*aw;
    const float pcy = acy + dy*ah;
    const float pw = aw*expf(dw);
    const float ph = ah*expf(dh);
    const float x1 = pcx - 0.5f*pw, y1 = pcy - 0.5f*ph;
    const float x2 = pcx + 0.5f*pw, y2 = pcy + 0.5f*ph;
    bx1[t]=x1; by1[t]=y1; bx2[t]=x2; by2[t]=y2;
    bar_[t] = fmaxf(x2-x1, 0.f)*fmaxf(y2-y1, 0.f);
  }
  __syncthreads();

  // ---- parallel 400x400 suppression bitmask ----
  for (int task=t; task<2800; task+=1024){
    const int i = task/7, w = task - (task/7)*7;
    unsigned long long m = 0ull;
    const float xi1=bx1[i], yi1=by1[i], xi2=bx2[i], yi2=by2[i], ai=bar_[i];
    const int j0 = w<<6;
    const int js = (j0 > i+1) ? j0 : (i+1);
    const int je = (j0+64 < 400) ? (j0+64) : 400;
    for (int j=js; j<je; ++j){
      const float ix1 = fmaxf(xi1, bx1[j]);
      const float iy1 = fmaxf(yi1, by1[j]);
      const float ix2 = fminf(xi2, bx2[j]);
      const float iy2 = fminf(yi2, by2[j]);
      const float inter = fmaxf(ix2-ix1, 0.f)*fmaxf(iy2-iy1, 0.f);
      const float iou = inter / fmaxf(ai + bar_[j] - inter, 1e-8f);
      if (iou > 0.6f) m |= (1ull << (j - j0));
    }
    mask[i][w] = m;
  }
  __syncthreads();

  // ---- serial suppression scan (word-parallel ANDs) + top-50 list ----
  if (t==0){
    unsigned long long keepw[7];
#pragma unroll
    for (int w=0;w<7;++w) keepw[w] = ~0ull;
    for (int i=0;i<400;++i){
      if ((keepw[i>>6] >> (i&63)) & 1ull){
#pragma unroll
        for (int w=0;w<7;++w) keepw[w] &= ~mask[i][w];
      }
    }
    int cnt=0;
    for (int i=0;i<400 && cnt<50;++i) if ( (keepw[i>>6]>>(i&63)) & 1ull) olist[cnt++]=i;
    for (int i=0;i<400 && cnt<50;++i) if (!((keepw[i>>6]>>(i&63)) & 1ull)) olist[cnt++]=i;
  }
  __syncthreads();

  if (t < 50){
    const int j = olist[t];
    float* o = out + (size_t)b*600 + (size_t)(lvl*50 + t)*4;
    o[0]=bx1[j]; o[1]=by1[j]; o[2]=bx2[j]; o[3]=by2[j];
  }
}

extern "C" void kernel_launch(void* const* d_in, const int* in_sizes, int n_in,
                              void* d_out, int out_size, void* d_ws, size_t ws_size,
                              hipStream_t stream) {
  (void)in_sizes; (void)n_in; (void)out_size; (void)ws_size;
  const float* p3     = (const float*)d_in[0];
  const float* p4     = (const float*)d_in[1];
  const float* p5     = (const float*)d_in[2];
  const float* w_stem = (const float*)d_in[3];
  const float* b_stem = (const float*)d_in[4];
  const float* w_obj  = (const float*)d_in[5];
  const float* b_obj  = (const float*)d_in[6];
  const float* w_box  = (const float*)d_in[7];
  const float* b_box  = (const float*)d_in[8];
  float* out = (float*)d_out;

  float* ws  = (float*)d_ws;
  float* wT  = ws;                    // 2304*256          = 589824
  float* sc3 = wT  + 589824;          // 8*128*128*3       = 393216
  float* sc4 = sc3 + 393216;          // 8*64*64*3         =  98304
  float* sc5 = sc4 + 98304;           // 8*32*32*3         =  24576
  float* dl3 = sc5 + 24576;           // 8*128*128*12      = 1572864
  float* dl4 = dl3 + 1572864;         // 8*64*64*12        = 393216
  float* dl5 = dl4 + 393216;          // 8*32*32*12        =  98304

  k_wtrans<<<dim3(2304), dim3(256), 0, stream>>>(w_stem, wT);

  k_stem<8><<<dim3(16,16,8), dim3(256), 0, stream>>>(p3, wT, b_stem, w_obj, b_obj, w_box, b_box, sc3, dl3, 128, 128);
  k_stem<8><<<dim3(8,8,8),   dim3(256), 0, stream>>>(p4, wT, b_stem, w_obj, b_obj, w_box, b_box, sc4, dl4, 64, 64);
  k_stem<4><<<dim3(4,8,8),   dim3(256), 0, stream>>>(p5, wT, b_stem, w_obj, b_obj, w_box, b_box, sc5, dl5, 32, 32);

  k_select<<<dim3(24), dim3(1024), 0, stream>>>(sc3, sc4, sc5, dl3, dl4, dl5, out);
}

// Round 4
// 19751.711 us; speedup vs baseline: 1.7535x; 1.7535x over previous
//
#include <hip/hip_runtime.h>
#include <math.h>
#include <stdint.h>

#define BBOX_CLAMP 4.135166556742356f
#define SQH 0.70710678118654752f
#define SQ2 1.41421356237309515f

__device__ __forceinline__ unsigned okey(float f){
  unsigned u = __float_as_uint(f);
  return (u & 0x80000000u) ? ~u : (u | 0x80000000u);
}

// ---------------- one-time weight transpose: wT[(cin*9+k)*256 + co] ----------------
__global__ void k_wtrans(const float* __restrict__ w, float* __restrict__ wT){
  const int ck = blockIdx.x;      // cin*9+k  (0..2303)
  const int co = threadIdx.x;     // 0..255
  wT[ck*256 + co] = w[co*2304 + ck];
}

// Row-stationary conv update with STRICTLY static acc indexing:
// r and kh are unrolled over literal bounds, py = r-kh is a compile-time
// constant, and the guard folds. Per output the fmaf chain order is
// cin -> kh(asc) -> kw(asc): bit-identical to the passing rounds.
template<int TH>
__device__ __forceinline__ void conv_rows(const float (* __restrict__ tile)[12],
                                          const float* __restrict__ wr,
                                          float* __restrict__ acc){
#pragma unroll
  for (int r=0; r<TH+2; ++r){
    const float4 q0 = *reinterpret_cast<const float4*>(&tile[r][0]);
    const float4 q1 = *reinterpret_cast<const float4*>(&tile[r][4]);
    const float4 q2 = *reinterpret_cast<const float4*>(&tile[r][8]);
    const float rw[12] = {q0.x,q0.y,q0.z,q0.w, q1.x,q1.y,q1.z,q1.w, q2.x,q2.y,q2.z,q2.w};
#pragma unroll
    for (int kh=0; kh<3; ++kh){
      const int py = r - kh;              // constant after unroll
      if (py >= 0 && py < TH){            // folds at compile time
#pragma unroll
        for (int px=0; px<8; ++px){
          float s = acc[py*8+px];         // static index
          s = fmaf(rw[px+0], wr[kh*3+0], s);
          s = fmaf(rw[px+1], wr[kh*3+1], s);
          s = fmaf(rw[px+2], wr[kh*3+2], s);
          acc[py*8+px] = s;
        }
      }
    }
  }
}

// ---------------- fused stem conv3x3+bias+relu + obj/box 1x1 heads ----------------
template<int TH>
__global__ __launch_bounds__(256, 4) void k_stem(
    const float* __restrict__ feat,   // [8][256][H][W]
    const float* __restrict__ wT,     // [2304][256]
    const float* __restrict__ bstem,  // [256]
    const float* __restrict__ wobj,   // [3][256]
    const float* __restrict__ bobj,   // [3]
    const float* __restrict__ wbox,   // [12][256]
    const float* __restrict__ bbox,   // [12]
    float* __restrict__ scores,       // [8][H*W*3]
    float* __restrict__ deltas,       // [8][H*W*12]
    const int H, const int W)
{
  __shared__ __align__(16) float in_t[2][TH+2][12];
  __shared__ float x_lds[32][257];

  const int tx0 = blockIdx.x*8, ty0 = blockIdx.y*TH;
  const int b = blockIdx.z;
  const int co = threadIdx.x;
  const size_t HW = (size_t)H*W;
  const float* fb = feat + (size_t)b*256*HW;

  constexpr int LC = (TH+2)*10;
  const int lty = co/10, ltx = co - (co/10)*10;
  const bool lactive = (co < LC);
  const int gy = ty0-1+lty, gx = tx0-1+ltx;
  const bool inb = lactive && (gy>=0 && gy<H && gx>=0 && gx<W);
  const float* gsrc = fb + ((size_t)(inb?gy:0)*W + (size_t)(inb?gx:0));

  float acc[TH*8];
#pragma unroll
  for (int i=0;i<TH*8;++i) acc[i]=0.f;

  // preload cin 0 tile + weights
  if (lactive) in_t[0][lty][ltx] = inb ? *gsrc : 0.f;
  float wr[9];
#pragma unroll
  for (int k=0;k<9;++k) wr[k] = wT[k*256+co];
  __syncthreads();

  for (int cin=0; cin<256; ++cin){
    const int buf = cin & 1;
    // prefetch next cin (issue-early): tile value -> pv, weights -> wn
    float pv = 0.f;
    float wn[9];
    if (cin < 255){
      if (inb) pv = gsrc[(size_t)(cin+1)*HW];
#pragma unroll
      for (int k=0;k<9;++k) wn[k] = wT[((size_t)(cin+1)*9+(size_t)k)*256+co];
    }

    conv_rows<TH>(in_t[buf], wr, acc);

    // write-late into the other buffer, then hand weights over
    if (cin < 255){
      if (lactive) in_t[buf^1][lty][ltx] = pv;
#pragma unroll
      for (int k=0;k<9;++k) wr[k] = wn[k];
    }
    __syncthreads();
  }

  // bias + relu
  const float bs = bstem[co];
#pragma unroll
  for (int i=0;i<TH*8;++i) acc[i] = fmaxf(acc[i]+bs, 0.f);

  // heads: groups of 32 pixels through LDS
  const int p_loc = co & 31;
  const int g = co >> 5;                 // 0..7
  const int oc0 = g*2, oc1 = g*2+1;      // oc in [0,16), 15 unused
  const float* wh0 = (oc0<3) ? (wobj + oc0*256) : (wbox + (oc0-3)*256);
  const float* wh1 = (oc1<3) ? (wobj + oc1*256) : ((oc1<15) ? (wbox + (oc1-3)*256) : wbox);
  const float bias0 = (oc0<3) ? bobj[oc0] : bbox[oc0-3];
  const float bias1 = (oc1<3) ? bobj[oc1] : ((oc1<15) ? bbox[oc1-3] : 0.f);

  constexpr int NH = (TH*8)/32;
#pragma unroll
  for (int half=0; half<NH; ++half){
    __syncthreads();
#pragma unroll
    for (int i=0;i<32;++i) x_lds[i][co] = acc[half*32 + i];
    __syncthreads();
    const int p  = half*32 + p_loc;
    const int py = p>>3, px = p&7;
    const int hh = ty0+py, ww = tx0+px;
    const size_t loc = (size_t)hh*W + ww;
    float s0 = 0.f, s1 = 0.f;
#pragma unroll 8
    for (int c=0;c<256;++c){
      const float xv = x_lds[p_loc][c];
      s0 = fmaf(xv, wh0[c], s0);
      s1 = fmaf(xv, wh1[c], s1);
    }
    s0 += bias0; s1 += bias1;
    if (oc0 < 3) scores[b*HW*3 + loc*3 + oc0] = s0;
    else         deltas[b*HW*12 + loc*12 + (oc0-3)] = s0;
    if (oc1 < 3) scores[b*HW*3 + loc*3 + oc1] = s1;
    else if (oc1 < 15) deltas[b*HW*12 + loc*12 + (oc1-3)] = s1;
  }
}

// ---------------- per (level,image): top-400 -> decode -> NMS -> top-50 ----------------
__global__ __launch_bounds__(1024) void k_select(
    const float* __restrict__ sc3, const float* __restrict__ sc4, const float* __restrict__ sc5,
    const float* __restrict__ dl3, const float* __restrict__ dl4, const float* __restrict__ dl5,
    float* __restrict__ out)
{
  const int lvl = blockIdx.x >> 3;
  const int b   = blockIdx.x & 7;
  int N, W; float stride; const float* sc; const float* dl;
  if (lvl==0){ N=49152; W=128; stride=8.f;  sc=sc3; dl=dl3; }
  else if (lvl==1){ N=12288; W=64; stride=16.f; sc=sc4; dl=dl4; }
  else { N=3072; W=32; stride=32.f; sc=sc5; dl=dl5; }
  sc += (size_t)b*N;
  dl += (size_t)b*(size_t)(N/3)*12;

  __shared__ unsigned hist[256];
  __shared__ unsigned s_prefix;
  __shared__ int s_need;
  __shared__ int s_cntc;
  __shared__ unsigned long long cand[1024];
  __shared__ int tk[400];
  __shared__ float bx1[400], by1[400], bx2[400], by2[400], bar_[400];
  __shared__ unsigned long long mask[400][7];
  __shared__ int olist[50];

  const int t = threadIdx.x;

  // ---- radix-select: find key K of the 400th-largest score ----
  if (t==0){ s_prefix=0u; s_need=400; }
  for (int pass=0; pass<4; ++pass){
    const int shift = 24 - 8*pass;
    if (t<256) hist[t]=0u;
    __syncthreads();
    const unsigned pref = s_prefix;
    for (int i=t; i<N; i+=1024){
      const unsigned k = okey(sc[i]);
      if (pass==0 || (k >> (shift+8)) == pref)
        atomicAdd(&hist[(k>>shift)&255u], 1u);
    }
    __syncthreads();
    if (t==0){
      int need = s_need, cum=0, bsel=0;
      for (int bb=255; bb>=0; --bb){
        const int h = (int)hist[bb];
        if (cum + h >= need){ bsel=bb; break; }
        cum += h;
      }
      s_prefix = (pref<<8) | (unsigned)bsel;
      s_need = need - cum;
    }
    __syncthreads();
  }
  const unsigned K = s_prefix;

  // ---- compact candidates: all keys >= K (count >= 400 by construction) ----
  if (t==0) s_cntc = 0;
  cand[t] = 0ull;
  __syncthreads();
  for (int i=t; i<N; i+=1024){
    const unsigned k = okey(sc[i]);
    if (k >= K){
      const int pos = atomicAdd(&s_cntc, 1);
      if (pos < 1024)
        cand[pos] = ((unsigned long long)k<<32) | (unsigned long long)(0xFFFFFFFFu - (unsigned)i);
    }
  }
  __syncthreads();

  // ---- bitonic sort 1024 descending: (key desc, idx asc) ----
  for (int kk=2; kk<=1024; kk<<=1){
    for (int j=kk>>1; j>0; j>>=1){
      const int ixj = t ^ j;
      if (ixj > t){
        const unsigned long long a = cand[t], c = cand[ixj];
        const bool descending = ((t & kk) == 0);
        if ((a < c) == descending){ cand[t]=c; cand[ixj]=a; }
      }
      __syncthreads();
    }
  }

  // ---- decode top-400 boxes ----
  if (t < 400){
    const unsigned long long c = cand[t];
    const int gi = (int)(0xFFFFFFFFu - (unsigned)(c & 0xFFFFFFFFull));
    tk[t] = gi;
    const int loc = gi/3, a = gi - loc*3;
    const int hh = loc / W, ww = loc - hh*W;
    const float cx = (ww + 0.5f)*stride, cy = (hh + 0.5f)*stride;
    const float size = stride*8.f;
    const float sq = (a==0) ? SQH : ((a==1) ? 1.f : SQ2);
    const float hw_ = 0.5f*(size/sq);    // half width  (w = size/sqrt(r))
    const float hv_ = 0.5f*(size*sq);    // half height (h = size*sqrt(r))
    const float ax1 = cx - hw_, ax2 = cx + hw_;
    const float ay1 = cy - hv_, ay2 = cy + hv_;
    const float aw = ax2 - ax1, ah = ay2 - ay1;
    const float acx = ax1 + 0.5f*aw, acy = ay1 + 0.5f*ah;
    const float* dd = dl + (size_t)loc*12 + a*4;
    const float dx = dd[0], dy = dd[1];
    const float dw = fminf(fmaxf(dd[2], -BBOX_CLAMP), BBOX_CLAMP);
    const float dh = fminf(fmaxf(dd[3], -BBOX_CLAMP), BBOX_CLAMP);
    const float pcx = acx + dx*aw;
    const float pcy = acy + dy*ah;
    const float pw = aw*expf(dw);
    const float ph = ah*expf(dh);
    const float x1 = pcx - 0.5f*pw, y1 = pcy - 0.5f*ph;
    const float x2 = pcx + 0.5f*pw, y2 = pcy + 0.5f*ph;
    bx1[t]=x1; by1[t]=y1; bx2[t]=x2; by2[t]=y2;
    bar_[t] = fmaxf(x2-x1, 0.f)*fmaxf(y2-y1, 0.f);
  }
  __syncthreads();

  // ---- parallel 400x400 suppression bitmask ----
  for (int task=t; task<2800; task+=1024){
    const int i = task/7, w = task - (task/7)*7;
    unsigned long long m = 0ull;
    const float xi1=bx1[i], yi1=by1[i], xi2=bx2[i], yi2=by2[i], ai=bar_[i];
    const int j0 = w<<6;
    const int js = (j0 > i+1) ? j0 : (i+1);
    const int je = (j0+64 < 400) ? (j0+64) : 400;
    for (int j=js; j<je; ++j){
      const float ix1 = fmaxf(xi1, bx1[j]);
      const float iy1 = fmaxf(yi1, by1[j]);
      const float ix2 = fminf(xi2, bx2[j]);
      const float iy2 = fminf(yi2, by2[j]);
      const float inter = fmaxf(ix2-ix1, 0.f)*fmaxf(iy2-iy1, 0.f);
      const float iou = inter / fmaxf(ai + bar_[j] - inter, 1e-8f);
      if (iou > 0.6f) m |= (1ull << (j - j0));
    }
    mask[i][w] = m;
  }
  __syncthreads();

  // ---- serial suppression scan (word-parallel ANDs) + top-50 list ----
  if (t==0){
    unsigned long long keepw[7];
#pragma unroll
    for (int w=0;w<7;++w) keepw[w] = ~0ull;
    for (int i=0;i<400;++i){
      if ((keepw[i>>6] >> (i&63)) & 1ull){
#pragma unroll
        for (int w=0;w<7;++w) keepw[w] &= ~mask[i][w];
      }
    }
    int cnt=0;
    for (int i=0;i<400 && cnt<50;++i) if ( (keepw[i>>6]>>(i&63)) & 1ull) olist[cnt++]=i;
    for (int i=0;i<400 && cnt<50;++i) if (!((keepw[i>>6]>>(i&63)) & 1ull)) olist[cnt++]=i;
  }
  __syncthreads();

  if (t < 50){
    const int j = olist[t];
    float* o = out + (size_t)b*600 + (size_t)(lvl*50 + t)*4;
    o[0]=bx1[j]; o[1]=by1[j]; o[2]=bx2[j]; o[3]=by2[j];
  }
}

extern "C" void kernel_launch(void* const* d_in, const int* in_sizes, int n_in,
                              void* d_out, int out_size, void* d_ws, size_t ws_size,
                              hipStream_t stream) {
  (void)in_sizes; (void)n_in; (void)out_size; (void)ws_size;
  const float* p3     = (const float*)d_in[0];
  const float* p4     = (const float*)d_in[1];
  const float* p5     = (const float*)d_in[2];
  const float* w_stem = (const float*)d_in[3];
  const float* b_stem = (const float*)d_in[4];
  const float* w_obj  = (const float*)d_in[5];
  const float* b_obj  = (const float*)d_in[6];
  const float* w_box  = (const float*)d_in[7];
  const float* b_box  = (const float*)d_in[8];
  float* out = (float*)d_out;

  float* ws  = (float*)d_ws;
  float* wT  = ws;                    // 2304*256          = 589824
  float* sc3 = wT  + 589824;          // 8*128*128*3       = 393216
  float* sc4 = sc3 + 393216;          // 8*64*64*3         =  98304
  float* sc5 = sc4 + 98304;           // 8*32*32*3         =  24576
  float* dl3 = sc5 + 24576;           // 8*128*128*12      = 1572864
  float* dl4 = dl3 + 1572864;         // 8*64*64*12        = 393216
  float* dl5 = dl4 + 393216;          // 8*32*32*12        =  98304

  k_wtrans<<<dim3(2304), dim3(256), 0, stream>>>(w_stem, wT);

  k_stem<8><<<dim3(16,16,8), dim3(256), 0, stream>>>(p3, wT, b_stem, w_obj, b_obj, w_box, b_box, sc3, dl3, 128, 128);
  k_stem<8><<<dim3(8,8,8),   dim3(256), 0, stream>>>(p4, wT, b_stem, w_obj, b_obj, w_box, b_box, sc4, dl4, 64, 64);
  k_stem<4><<<dim3(4,8,8),   dim3(256), 0, stream>>>(p5, wT, b_stem, w_obj, b_obj, w_box, b_box, sc5, dl5, 32, 32);

  k_select<<<dim3(24), dim3(1024), 0, stream>>>(sc3, sc4, sc5, dl3, dl4, dl5, out);
}

// Round 5
// 11429.826 us; speedup vs baseline: 3.0302x; 1.7281x over previous
//
#include <hip/hip_runtime.h>
#include <math.h>
#include <stdint.h>

#define BBOX_CLAMP 4.135166556742356f
#define SQH 0.70710678118654752f
#define SQ2 1.41421356237309515f

__device__ __forceinline__ unsigned okey(float f){
  unsigned u = __float_as_uint(f);
  return (u & 0x80000000u) ? ~u : (u | 0x80000000u);
}

// ---------------- one-time weight transpose: wT[(cin*9+k)*256 + co] ----------------
__global__ void k_wtrans(const float* __restrict__ w, float* __restrict__ wT){
  const int ck = blockIdx.x;      // cin*9+k  (0..2303)
  const int co = threadIdx.x;     // 0..255
  wT[ck*256 + co] = w[co*2304 + ck];
}

// ---------------- fused stem conv3x3+bias+relu + obj/box 1x1 heads ----------------
// Row-stationary conv, fully inline (NO helper function, NO pointer-passed acc:
// r3/r4 spilled acc to scratch through the call boundary). All acc indices are
// literal after unroll; guards are if-constexpr on macro-literal row numbers.
// Per-output fmaf order: cin asc -> kh asc -> kw asc (bit-identical to r1/r2).
template<int TH>
__global__ __launch_bounds__(256, 3) void k_stem(
    const float* __restrict__ feat,   // [8][256][H][W]
    const float* __restrict__ wT,     // [2304][256]
    const float* __restrict__ bstem,  // [256]
    const float* __restrict__ wobj,   // [3][256]
    const float* __restrict__ bobj,   // [3]
    const float* __restrict__ wbox,   // [12][256]
    const float* __restrict__ bbox,   // [12]
    float* __restrict__ scores,       // [8][H*W*3]
    float* __restrict__ deltas,       // [8][H*W*12]
    const int H, const int W)
{
  __shared__ __align__(16) float in_t[2][TH+2][12];
  __shared__ float x_lds[32][257];

  const int tx0 = blockIdx.x*8, ty0 = blockIdx.y*TH;
  const int b = blockIdx.z;
  const int co = threadIdx.x;
  const size_t HW = (size_t)H*W;
  const float* fb = feat + (size_t)b*256*HW;

  constexpr int LC = (TH+2)*10;
  const int lty = co/10, ltx = co - (co/10)*10;
  const bool lactive = (co < LC);
  const int gy = ty0-1+lty, gx = tx0-1+ltx;
  const bool inb = lactive && (gy>=0 && gy<H && gx>=0 && gx<W);
  const float* gsrc = fb + ((size_t)(inb?gy:0)*W + (size_t)(inb?gx:0));

  float acc[TH*8];
#pragma unroll
  for (int i=0;i<TH*8;++i) acc[i]=0.f;

  // preload cin 0 tile + weights
  if (lactive) in_t[0][lty][ltx] = inb ? *gsrc : 0.f;
  float wr[9];
#pragma unroll
  for (int k=0;k<9;++k) wr[k] = wT[k*256+co];
  __syncthreads();

#define UPD(PY, KH) { \
  _Pragma("unroll") \
  for (int px=0; px<8; ++px){ \
    float s = acc[(PY)*8+px]; \
    s = fmaf(rw[px+0], wr[(KH)*3+0], s); \
    s = fmaf(rw[px+1], wr[(KH)*3+1], s); \
    s = fmaf(rw[px+2], wr[(KH)*3+2], s); \
    acc[(PY)*8+px] = s; \
  } }

#define DOROW(R) \
  if constexpr ((R) < TH+2) { \
    const float4 q0 = *reinterpret_cast<const float4*>(&in_t[buf][(R)][0]); \
    const float4 q1 = *reinterpret_cast<const float4*>(&in_t[buf][(R)][4]); \
    const float4 q2 = *reinterpret_cast<const float4*>(&in_t[buf][(R)][8]); \
    const float rw[12] = {q0.x,q0.y,q0.z,q0.w, q1.x,q1.y,q1.z,q1.w, q2.x,q2.y,q2.z,q2.w}; \
    if constexpr ((R) <= TH-1)               UPD((R),   0) \
    if constexpr ((R) >= 1 && (R)-1 <= TH-1) UPD((R)-1, 1) \
    if constexpr ((R) >= 2)                  UPD((R)-2, 2) \
  }

  for (int cin=0; cin<256; ++cin){
    const int buf = cin & 1;
    // prefetch next cin (issue-early): tile value -> pv, weights -> wn
    float pv = 0.f;
    float wn[9];
    if (cin < 255){
      if (inb) pv = gsrc[(size_t)(cin+1)*HW];
#pragma unroll
      for (int k=0;k<9;++k) wn[k] = wT[((size_t)(cin+1)*9+(size_t)k)*256+co];
    }

    DOROW(0) DOROW(1) DOROW(2) DOROW(3) DOROW(4)
    DOROW(5) DOROW(6) DOROW(7) DOROW(8) DOROW(9)

    // write-late into the other buffer, then hand weights over
    if (cin < 255){
      if (lactive) in_t[buf^1][lty][ltx] = pv;
#pragma unroll
      for (int k=0;k<9;++k) wr[k] = wn[k];
    }
    __syncthreads();
  }
#undef DOROW
#undef UPD

  // bias + relu
  const float bs = bstem[co];
#pragma unroll
  for (int i=0;i<TH*8;++i) acc[i] = fmaxf(acc[i]+bs, 0.f);

  // heads: groups of 32 pixels through LDS
  const int p_loc = co & 31;
  const int g = co >> 5;                 // 0..7
  const int oc0 = g*2, oc1 = g*2+1;      // oc in [0,16), 15 unused
  const float* wh0 = (oc0<3) ? (wobj + oc0*256) : (wbox + (oc0-3)*256);
  const float* wh1 = (oc1<3) ? (wobj + oc1*256) : ((oc1<15) ? (wbox + (oc1-3)*256) : wbox);
  const float bias0 = (oc0<3) ? bobj[oc0] : bbox[oc0-3];
  const float bias1 = (oc1<3) ? bobj[oc1] : ((oc1<15) ? bbox[oc1-3] : 0.f);

  constexpr int NH = (TH*8)/32;
#pragma unroll
  for (int half=0; half<NH; ++half){
    __syncthreads();
#pragma unroll
    for (int i=0;i<32;++i) x_lds[i][co] = acc[half*32 + i];
    __syncthreads();
    const int p  = half*32 + p_loc;
    const int py = p>>3, px = p&7;
    const int hh = ty0+py, ww = tx0+px;
    const size_t loc = (size_t)hh*W + ww;
    float s0 = 0.f, s1 = 0.f;
#pragma unroll 8
    for (int c=0;c<256;++c){
      const float xv = x_lds[p_loc][c];
      s0 = fmaf(xv, wh0[c], s0);
      s1 = fmaf(xv, wh1[c], s1);
    }
    s0 += bias0; s1 += bias1;
    if (oc0 < 3) scores[b*HW*3 + loc*3 + oc0] = s0;
    else         deltas[b*HW*12 + loc*12 + (oc0-3)] = s0;
    if (oc1 < 3) scores[b*HW*3 + loc*3 + oc1] = s1;
    else if (oc1 < 15) deltas[b*HW*12 + loc*12 + (oc1-3)] = s1;
  }
}

// ---------------- per (level,image): top-400 -> decode -> NMS -> top-50 ----------------
__global__ __launch_bounds__(1024) void k_select(
    const float* __restrict__ sc3, const float* __restrict__ sc4, const float* __restrict__ sc5,
    const float* __restrict__ dl3, const float* __restrict__ dl4, const float* __restrict__ dl5,
    float* __restrict__ out)
{
  const int lvl = blockIdx.x >> 3;
  const int b   = blockIdx.x & 7;
  int N, W; float stride; const float* sc; const float* dl;
  if (lvl==0){ N=49152; W=128; stride=8.f;  sc=sc3; dl=dl3; }
  else if (lvl==1){ N=12288; W=64; stride=16.f; sc=sc4; dl=dl4; }
  else { N=3072; W=32; stride=32.f; sc=sc5; dl=dl5; }
  sc += (size_t)b*N;
  dl += (size_t)b*(size_t)(N/3)*12;

  __shared__ unsigned hist[256];
  __shared__ unsigned s_prefix;
  __shared__ int s_need;
  __shared__ int s_cntc;
  __shared__ unsigned long long cand[1024];
  __shared__ int tk[400];
  __shared__ float bx1[400], by1[400], bx2[400], by2[400], bar_[400];
  __shared__ unsigned long long mask[400][7];
  __shared__ int olist[50];

  const int t = threadIdx.x;

  // ---- radix-select: find key K of the 400th-largest score ----
  if (t==0){ s_prefix=0u; s_need=400; }
  for (int pass=0; pass<4; ++pass){
    const int shift = 24 - 8*pass;
    if (t<256) hist[t]=0u;
    __syncthreads();
    const unsigned pref = s_prefix;
    for (int i=t; i<N; i+=1024){
      const unsigned k = okey(sc[i]);
      if (pass==0 || (k >> (shift+8)) == pref)
        atomicAdd(&hist[(k>>shift)&255u], 1u);
    }
    __syncthreads();
    if (t==0){
      int need = s_need, cum=0, bsel=0;
      for (int bb=255; bb>=0; --bb){
        const int h = (int)hist[bb];
        if (cum + h >= need){ bsel=bb; break; }
        cum += h;
      }
      s_prefix = (pref<<8) | (unsigned)bsel;
      s_need = need - cum;
    }
    __syncthreads();
  }
  const unsigned K = s_prefix;

  // ---- compact candidates: all keys >= K (count >= 400 by construction) ----
  if (t==0) s_cntc = 0;
  cand[t] = 0ull;
  __syncthreads();
  for (int i=t; i<N; i+=1024){
    const unsigned k = okey(sc[i]);
    if (k >= K){
      const int pos = atomicAdd(&s_cntc, 1);
      if (pos < 1024)
        cand[pos] = ((unsigned long long)k<<32) | (unsigned long long)(0xFFFFFFFFu - (unsigned)i);
    }
  }
  __syncthreads();

  // ---- bitonic sort 1024 descending: (key desc, idx asc) ----
  for (int kk=2; kk<=1024; kk<<=1){
    for (int j=kk>>1; j>0; j>>=1){
      const int ixj = t ^ j;
      if (ixj > t){
        const unsigned long long a = cand[t], c = cand[ixj];
        const bool descending = ((t & kk) == 0);
        if ((a < c) == descending){ cand[t]=c; cand[ixj]=a; }
      }
      __syncthreads();
    }
  }

  // ---- decode top-400 boxes ----
  if (t < 400){
    const unsigned long long c = cand[t];
    const int gi = (int)(0xFFFFFFFFu - (unsigned)(c & 0xFFFFFFFFull));
    tk[t] = gi;
    const int loc = gi/3, a = gi - loc*3;
    const int hh = loc / W, ww = loc - hh*W;
    const float cx = (ww + 0.5f)*stride, cy = (hh + 0.5f)*stride;
    const float size = stride*8.f;
    const float sq = (a==0) ? SQH : ((a==1) ? 1.f : SQ2);
    const float hw_ = 0.5f*(size/sq);    // half width  (w = size/sqrt(r))
    const float hv_ = 0.5f*(size*sq);    // half height (h = size*sqrt(r))
    const float ax1 = cx - hw_, ax2 = cx + hw_;
    const float ay1 = cy - hv_, ay2 = cy + hv_;
    const float aw = ax2 - ax1, ah = ay2 - ay1;
    const float acx = ax1 + 0.5f*aw, acy = ay1 + 0.5f*ah;
    const float* dd = dl + (size_t)loc*12 + a*4;
    const float dx = dd[0], dy = dd[1];
    const float dw = fminf(fmaxf(dd[2], -BBOX_CLAMP), BBOX_CLAMP);
    const float dh = fminf(fmaxf(dd[3], -BBOX_CLAMP), BBOX_CLAMP);
    const float pcx = acx + dx*aw;
    const float pcy = acy + dy*ah;
    const float pw = aw*expf(dw);
    const float ph = ah*expf(dh);
    const float x1 = pcx - 0.5f*pw, y1 = pcy - 0.5f*ph;
    const float x2 = pcx + 0.5f*pw, y2 = pcy + 0.5f*ph;
    bx1[t]=x1; by1[t]=y1; bx2[t]=x2; by2[t]=y2;
    bar_[t] = fmaxf(x2-x1, 0.f)*fmaxf(y2-y1, 0.f);
  }
  __syncthreads();

  // ---- parallel 400x400 suppression bitmask ----
  for (int task=t; task<2800; task+=1024){
    const int i = task/7, w = task - (task/7)*7;
    unsigned long long m = 0ull;
    const float xi1=bx1[i], yi1=by1[i], xi2=bx2[i], yi2=by2[i], ai=bar_[i];
    const int j0 = w<<6;
    const int js = (j0 > i+1) ? j0 : (i+1);
    const int je = (j0+64 < 400) ? (j0+64) : 400;
    for (int j=js; j<je; ++j){
      const float ix1 = fmaxf(xi1, bx1[j]);
      const float iy1 = fmaxf(yi1, by1[j]);
      const float ix2 = fminf(xi2, bx2[j]);
      const float iy2 = fminf(yi2, by2[j]);
      const float inter = fmaxf(ix2-ix1, 0.f)*fmaxf(iy2-iy1, 0.f);
      const float iou = inter / fmaxf(ai + bar_[j] - inter, 1e-8f);
      if (iou > 0.6f) m |= (1ull << (j - j0));
    }
    mask[i][w] = m;
  }
  __syncthreads();

  // ---- serial suppression scan (word-parallel ANDs) + top-50 list ----
  if (t==0){
    unsigned long long keepw[7];
#pragma unroll
    for (int w=0;w<7;++w) keepw[w] = ~0ull;
    for (int i=0;i<400;++i){
      if ((keepw[i>>6] >> (i&63)) & 1ull){
#pragma unroll
        for (int w=0;w<7;++w) keepw[w] &= ~mask[i][w];
      }
    }
    int cnt=0;
    for (int i=0;i<400 && cnt<50;++i) if ( (keepw[i>>6]>>(i&63)) & 1ull) olist[cnt++]=i;
    for (int i=0;i<400 && cnt<50;++i) if (!((keepw[i>>6]>>(i&63)) & 1ull)) olist[cnt++]=i;
  }
  __syncthreads();

  if (t < 50){
    const int j = olist[t];
    float* o = out + (size_t)b*600 + (size_t)(lvl*50 + t)*4;
    o[0]=bx1[j]; o[1]=by1[j]; o[2]=bx2[j]; o[3]=by2[j];
  }
}

extern "C" void kernel_launch(void* const* d_in, const int* in_sizes, int n_in,
                              void* d_out, int out_size, void* d_ws, size_t ws_size,
                              hipStream_t stream) {
  (void)in_sizes; (void)n_in; (void)out_size; (void)ws_size;
  const float* p3     = (const float*)d_in[0];
  const float* p4     = (const float*)d_in[1];
  const float* p5     = (const float*)d_in[2];
  const float* w_stem = (const float*)d_in[3];
  const float* b_stem = (const float*)d_in[4];
  const float* w_obj  = (const float*)d_in[5];
  const float* b_obj  = (const float*)d_in[6];
  const float* w_box  = (const float*)d_in[7];
  const float* b_box  = (const float*)d_in[8];
  float* out = (float*)d_out;

  float* ws  = (float*)d_ws;
  float* wT  = ws;                    // 2304*256          = 589824
  float* sc3 = wT  + 589824;          // 8*128*128*3       = 393216
  float* sc4 = sc3 + 393216;          // 8*64*64*3         =  98304
  float* sc5 = sc4 + 98304;           // 8*32*32*3         =  24576
  float* dl3 = sc5 + 24576;           // 8*128*128*12      = 1572864
  float* dl4 = dl3 + 1572864;         // 8*64*64*12        = 393216
  float* dl5 = dl4 + 393216;          // 8*32*32*12        =  98304

  k_wtrans<<<dim3(2304), dim3(256), 0, stream>>>(w_stem, wT);

  k_stem<8><<<dim3(16,16,8), dim3(256), 0, stream>>>(p3, wT, b_stem, w_obj, b_obj, w_box, b_box, sc3, dl3, 128, 128);
  k_stem<8><<<dim3(8,8,8),   dim3(256), 0, stream>>>(p4, wT, b_stem, w_obj, b_obj, w_box, b_box, sc4, dl4, 64, 64);
  k_stem<4><<<dim3(4,8,8),   dim3(256), 0, stream>>>(p5, wT, b_stem, w_obj, b_obj, w_box, b_box, sc5, dl5, 32, 32);

  k_select<<<dim3(24), dim3(1024), 0, stream>>>(sc3, sc4, sc5, dl3, dl4, dl5, out);
}

// Round 6
// 3898.048 us; speedup vs baseline: 8.8853x; 2.9322x over previous
//
#include <hip/hip_runtime.h>
#include <math.h>
#include <stdint.h>

#define BBOX_CLAMP 4.135166556742356f
#define SQH 0.70710678118654752f
#define SQ2 1.41421356237309515f

__device__ __forceinline__ unsigned okey(float f){
  unsigned u = __float_as_uint(f);
  return (u & 0x80000000u) ? ~u : (u | 0x80000000u);
}

// ---------------- one-time weight transpose: wT[(cin*9+k)*256 + co] ----------------
__global__ void k_wtrans(const float* __restrict__ w, float* __restrict__ wT){
  const int ck = blockIdx.x;      // cin*9+k  (0..2303)
  const int co = threadIdx.x;     // 0..255
  wT[ck*256 + co] = w[co*2304 + ck];
}

// ---------------- fused stem conv3x3+bias+relu + obj/box 1x1 heads ----------------
// Row-stationary conv, fully inline. CRITICAL: plain __launch_bounds__(256) with
// NO min-waves argument — r2/r3/r4 all force-spilled the 64-float accumulator to
// scratch whenever the min-waves arg was present (VGPR clamped to 64/84, WRITE_SIZE
// in the tens of GB); r0/r1 without it never spilled.
// Per-output fmaf order: cin asc -> kh asc -> kw asc (bit-identical to all passing rounds).
template<int TH>
__global__ __launch_bounds__(256) void k_stem(
    const float* __restrict__ feat,   // [8][256][H][W]
    const float* __restrict__ wT,     // [2304][256]
    const float* __restrict__ bstem,  // [256]
    const float* __restrict__ wobj,   // [3][256]
    const float* __restrict__ bobj,   // [3]
    const float* __restrict__ wbox,   // [12][256]
    const float* __restrict__ bbox,   // [12]
    float* __restrict__ scores,       // [8][H*W*3]
    float* __restrict__ deltas,       // [8][H*W*12]
    const int H, const int W)
{
  __shared__ __align__(16) float in_a[TH+2][12];
  __shared__ __align__(16) float in_b[TH+2][12];
  __shared__ float x_lds[32][257];

  const int tx0 = blockIdx.x*8, ty0 = blockIdx.y*TH;
  const int b = blockIdx.z;
  const int co = threadIdx.x;
  const size_t HW = (size_t)H*W;
  const float* fb = feat + (size_t)b*256*HW;

  constexpr int LC = (TH+2)*10;
  const int lty = co/10, ltx = co - (co/10)*10;
  const bool lactive = (co < LC);
  const int gy = ty0-1+lty, gx = tx0-1+ltx;
  const bool inb = lactive && (gy>=0 && gy<H && gx>=0 && gx<W);
  const float* gsrc = fb + ((size_t)(inb?gy:0)*W + (size_t)(inb?gx:0));

  float acc[TH*8];
#pragma unroll
  for (int i=0;i<TH*8;++i) acc[i]=0.f;

  // preload cin 0: tile -> in_a, weights -> wa
  if (lactive) in_a[lty][ltx] = inb ? *gsrc : 0.f;
  float wa[9], wb[9];
  const float* wp = wT + co;
#pragma unroll
  for (int k=0;k<9;++k) wa[k] = wp[k*256];
  wp += 9*256;                       // now points at cin 1 weights
  const float* gn = gsrc + HW;       // next tile value (cin 1)
  __syncthreads();

#define UPD(PY, KH, WR) { \
  _Pragma("unroll") \
  for (int px=0; px<8; ++px){ \
    float s = acc[(PY)*8+px]; \
    s = fmaf(rw[px+0], WR[(KH)*3+0], s); \
    s = fmaf(rw[px+1], WR[(KH)*3+1], s); \
    s = fmaf(rw[px+2], WR[(KH)*3+2], s); \
    acc[(PY)*8+px] = s; \
  } }

#define DOROW(R, TILE, WR) \
  if constexpr ((R) < TH+2) { \
    const float4 q0 = *reinterpret_cast<const float4*>(&TILE[(R)][0]); \
    const float4 q1 = *reinterpret_cast<const float4*>(&TILE[(R)][4]); \
    const float4 q2 = *reinterpret_cast<const float4*>(&TILE[(R)][8]); \
    const float rw[12] = {q0.x,q0.y,q0.z,q0.w, q1.x,q1.y,q1.z,q1.w, q2.x,q2.y,q2.z,q2.w}; \
    if constexpr ((R) <= TH-1)               UPD((R),   0, WR) \
    if constexpr ((R) >= 1 && (R)-1 <= TH-1) UPD((R)-1, 1, WR) \
    if constexpr ((R) >= 2)                  UPD((R)-2, 2, WR) \
  }

#define DOROWS(TILE, WR) \
  DOROW(0,TILE,WR) DOROW(1,TILE,WR) DOROW(2,TILE,WR) DOROW(3,TILE,WR) DOROW(4,TILE,WR) \
  DOROW(5,TILE,WR) DOROW(6,TILE,WR) DOROW(7,TILE,WR) DOROW(8,TILE,WR) DOROW(9,TILE,WR)

  for (int it=0; it<128; ++it){
    // ---- cin 2it (tile in_a, weights wa); prefetch cin 2it+1 ----
    float pv = 0.f;
    if (inb) pv = gn[0];
#pragma unroll
    for (int k=0;k<9;++k) wb[k] = wp[k*256];

    DOROWS(in_a, wa)

    if (lactive) in_b[lty][ltx] = pv;   // write-late
    __syncthreads();

    // ---- cin 2it+1 (tile in_b, weights wb); prefetch cin 2it+2 ----
    pv = 0.f;
    if (it < 127){
      if (inb) pv = gn[HW];
#pragma unroll
      for (int k=0;k<9;++k) wa[k] = wp[(9+k)*256];
    }

    DOROWS(in_b, wb)

    if (it < 127){
      if (lactive) in_a[lty][ltx] = pv;
    }
    __syncthreads();

    gn += 2*HW;
    wp += 18*256;
  }
#undef DOROWS
#undef DOROW
#undef UPD

  // bias + relu
  const float bs = bstem[co];
#pragma unroll
  for (int i=0;i<TH*8;++i) acc[i] = fmaxf(acc[i]+bs, 0.f);

  // heads: groups of 32 pixels through LDS
  const int p_loc = co & 31;
  const int g = co >> 5;                 // 0..7
  const int oc0 = g*2, oc1 = g*2+1;      // oc in [0,16), 15 unused
  const float* wh0 = (oc0<3) ? (wobj + oc0*256) : (wbox + (oc0-3)*256);
  const float* wh1 = (oc1<3) ? (wobj + oc1*256) : ((oc1<15) ? (wbox + (oc1-3)*256) : wbox);
  const float bias0 = (oc0<3) ? bobj[oc0] : bbox[oc0-3];
  const float bias1 = (oc1<3) ? bobj[oc1] : ((oc1<15) ? bbox[oc1-3] : 0.f);

  constexpr int NH = (TH*8)/32;
#pragma unroll
  for (int half=0; half<NH; ++half){
    __syncthreads();
#pragma unroll
    for (int i=0;i<32;++i) x_lds[i][co] = acc[half*32 + i];
    __syncthreads();
    const int p  = half*32 + p_loc;
    const int py = p>>3, px = p&7;
    const int hh = ty0+py, ww = tx0+px;
    const size_t loc = (size_t)hh*W + ww;
    float s0 = 0.f, s1 = 0.f;
#pragma unroll 8
    for (int c=0;c<256;++c){
      const float xv = x_lds[p_loc][c];
      s0 = fmaf(xv, wh0[c], s0);
      s1 = fmaf(xv, wh1[c], s1);
    }
    s0 += bias0; s1 += bias1;
    if (oc0 < 3) scores[b*HW*3 + loc*3 + oc0] = s0;
    else         deltas[b*HW*12 + loc*12 + (oc0-3)] = s0;
    if (oc1 < 3) scores[b*HW*3 + loc*3 + oc1] = s1;
    else if (oc1 < 15) deltas[b*HW*12 + loc*12 + (oc1-3)] = s1;
  }
}

// ---------------- per (level,image): top-400 -> decode -> NMS -> top-50 ----------------
__global__ __launch_bounds__(1024) void k_select(
    const float* __restrict__ sc3, const float* __restrict__ sc4, const float* __restrict__ sc5,
    const float* __restrict__ dl3, const float* __restrict__ dl4, const float* __restrict__ dl5,
    float* __restrict__ out)
{
  const int lvl = blockIdx.x >> 3;
  const int b   = blockIdx.x & 7;
  int N, W; float stride; const float* sc; const float* dl;
  if (lvl==0){ N=49152; W=128; stride=8.f;  sc=sc3; dl=dl3; }
  else if (lvl==1){ N=12288; W=64; stride=16.f; sc=sc4; dl=dl4; }
  else { N=3072; W=32; stride=32.f; sc=sc5; dl=dl5; }
  sc += (size_t)b*N;
  dl += (size_t)b*(size_t)(N/3)*12;

  __shared__ unsigned hist[256];
  __shared__ unsigned s_prefix;
  __shared__ int s_need;
  __shared__ int s_cntc;
  __shared__ unsigned long long cand[1024];
  __shared__ int tk[400];
  __shared__ float bx1[400], by1[400], bx2[400], by2[400], bar_[400];
  __shared__ unsigned long long mask[400][7];
  __shared__ int olist[50];

  const int t = threadIdx.x;

  // ---- radix-select: find key K of the 400th-largest score ----
  if (t==0){ s_prefix=0u; s_need=400; }
  for (int pass=0; pass<4; ++pass){
    const int shift = 24 - 8*pass;
    if (t<256) hist[t]=0u;
    __syncthreads();
    const unsigned pref = s_prefix;
    for (int i=t; i<N; i+=1024){
      const unsigned k = okey(sc[i]);
      if (pass==0 || (k >> (shift+8)) == pref)
        atomicAdd(&hist[(k>>shift)&255u], 1u);
    }
    __syncthreads();
    if (t==0){
      int need = s_need, cum=0, bsel=0;
      for (int bb=255; bb>=0; --bb){
        const int h = (int)hist[bb];
        if (cum + h >= need){ bsel=bb; break; }
        cum += h;
      }
      s_prefix = (pref<<8) | (unsigned)bsel;
      s_need = need - cum;
    }
    __syncthreads();
  }
  const unsigned K = s_prefix;

  // ---- compact candidates: all keys >= K (count >= 400 by construction) ----
  if (t==0) s_cntc = 0;
  cand[t] = 0ull;
  __syncthreads();
  for (int i=t; i<N; i+=1024){
    const unsigned k = okey(sc[i]);
    if (k >= K){
      const int pos = atomicAdd(&s_cntc, 1);
      if (pos < 1024)
        cand[pos] = ((unsigned long long)k<<32) | (unsigned long long)(0xFFFFFFFFu - (unsigned)i);
    }
  }
  __syncthreads();

  // ---- bitonic sort 1024 descending: (key desc, idx asc) ----
  for (int kk=2; kk<=1024; kk<<=1){
    for (int j=kk>>1; j>0; j>>=1){
      const int ixj = t ^ j;
      if (ixj > t){
        const unsigned long long a = cand[t], c = cand[ixj];
        const bool descending = ((t & kk) == 0);
        if ((a < c) == descending){ cand[t]=c; cand[ixj]=a; }
      }
      __syncthreads();
    }
  }

  // ---- decode top-400 boxes ----
  if (t < 400){
    const unsigned long long c = cand[t];
    const int gi = (int)(0xFFFFFFFFu - (unsigned)(c & 0xFFFFFFFFull));
    tk[t] = gi;
    const int loc = gi/3, a = gi - loc*3;
    const int hh = loc / W, ww = loc - hh*W;
    const float cx = (ww + 0.5f)*stride, cy = (hh + 0.5f)*stride;
    const float size = stride*8.f;
    const float sq = (a==0) ? SQH : ((a==1) ? 1.f : SQ2);
    const float hw_ = 0.5f*(size/sq);    // half width  (w = size/sqrt(r))
    const float hv_ = 0.5f*(size*sq);    // half height (h = size*sqrt(r))
    const float ax1 = cx - hw_, ax2 = cx + hw_;
    const float ay1 = cy - hv_, ay2 = cy + hv_;
    const float aw = ax2 - ax1, ah = ay2 - ay1;
    const float acx = ax1 + 0.5f*aw, acy = ay1 + 0.5f*ah;
    const float* dd = dl + (size_t)loc*12 + a*4;
    const float dx = dd[0], dy = dd[1];
    const float dw = fminf(fmaxf(dd[2], -BBOX_CLAMP), BBOX_CLAMP);
    const float dh = fminf(fmaxf(dd[3], -BBOX_CLAMP), BBOX_CLAMP);
    const float pcx = acx + dx*aw;
    const float pcy = acy + dy*ah;
    const float pw = aw*expf(dw);
    const float ph = ah*expf(dh);
    const float x1 = pcx - 0.5f*pw, y1 = pcy - 0.5f*ph;
    const float x2 = pcx + 0.5f*pw, y2 = pcy + 0.5f*ph;
    bx1[t]=x1; by1[t]=y1; bx2[t]=x2; by2[t]=y2;
    bar_[t] = fmaxf(x2-x1, 0.f)*fmaxf(y2-y1, 0.f);
  }
  __syncthreads();

  // ---- parallel 400x400 suppression bitmask ----
  for (int task=t; task<2800; task+=1024){
    const int i = task/7, w = task - (task/7)*7;
    unsigned long long m = 0ull;
    const float xi1=bx1[i], yi1=by1[i], xi2=bx2[i], yi2=by2[i], ai=bar_[i];
    const int j0 = w<<6;
    const int js = (j0 > i+1) ? j0 : (i+1);
    const int je = (j0+64 < 400) ? (j0+64) : 400;
    for (int j=js; j<je; ++j){
      const float ix1 = fmaxf(xi1, bx1[j]);
      const float iy1 = fmaxf(yi1, by1[j]);
      const float ix2 = fminf(xi2, bx2[j]);
      const float iy2 = fminf(yi2, by2[j]);
      const float inter = fmaxf(ix2-ix1, 0.f)*fmaxf(iy2-iy1, 0.f);
      const float iou = inter / fmaxf(ai + bar_[j] - inter, 1e-8f);
      if (iou > 0.6f) m |= (1ull << (j - j0));
    }
    mask[i][w] = m;
  }
  __syncthreads();

  // ---- serial suppression scan (word-parallel ANDs) + top-50 list ----
  if (t==0){
    unsigned long long keepw[7];
#pragma unroll
    for (int w=0;w<7;++w) keepw[w] = ~0ull;
    for (int i=0;i<400;++i){
      if ((keepw[i>>6] >> (i&63)) & 1ull){
#pragma unroll
        for (int w=0;w<7;++w) keepw[w] &= ~mask[i][w];
      }
    }
    int cnt=0;
    for (int i=0;i<400 && cnt<50;++i) if ( (keepw[i>>6]>>(i&63)) & 1ull) olist[cnt++]=i;
    for (int i=0;i<400 && cnt<50;++i) if (!((keepw[i>>6]>>(i&63)) & 1ull)) olist[cnt++]=i;
  }
  __syncthreads();

  if (t < 50){
    const int j = olist[t];
    float* o = out + (size_t)b*600 + (size_t)(lvl*50 + t)*4;
    o[0]=bx1[j]; o[1]=by1[j]; o[2]=bx2[j]; o[3]=by2[j];
  }
}

extern "C" void kernel_launch(void* const* d_in, const int* in_sizes, int n_in,
                              void* d_out, int out_size, void* d_ws, size_t ws_size,
                              hipStream_t stream) {
  (void)in_sizes; (void)n_in; (void)out_size; (void)ws_size;
  const float* p3     = (const float*)d_in[0];
  const float* p4     = (const float*)d_in[1];
  const float* p5     = (const float*)d_in[2];
  const float* w_stem = (const float*)d_in[3];
  const float* b_stem = (const float*)d_in[4];
  const float* w_obj  = (const float*)d_in[5];
  const float* b_obj  = (const float*)d_in[6];
  const float* w_box  = (const float*)d_in[7];
  const float* b_box  = (const float*)d_in[8];
  float* out = (float*)d_out;

  float* ws  = (float*)d_ws;
  float* wT  = ws;                    // 2304*256          = 589824
  float* sc3 = wT  + 589824;          // 8*128*128*3       = 393216
  float* sc4 = sc3 + 393216;          // 8*64*64*3         =  98304
  float* sc5 = sc4 + 98304;           // 8*32*32*3         =  24576
  float* dl3 = sc5 + 24576;           // 8*128*128*12      = 1572864
  float* dl4 = dl3 + 1572864;         // 8*64*64*12        = 393216
  float* dl5 = dl4 + 393216;          // 8*32*32*12        =  98304

  k_wtrans<<<dim3(2304), dim3(256), 0, stream>>>(w_stem, wT);

  k_stem<8><<<dim3(16,16,8), dim3(256), 0, stream>>>(p3, wT, b_stem, w_obj, b_obj, w_box, b_box, sc3, dl3, 128, 128);
  k_stem<8><<<dim3(8,8,8),   dim3(256), 0, stream>>>(p4, wT, b_stem, w_obj, b_obj, w_box, b_box, sc4, dl4, 64, 64);
  k_stem<4><<<dim3(4,8,8),   dim3(256), 0, stream>>>(p5, wT, b_stem, w_obj, b_obj, w_box, b_box, sc5, dl5, 32, 32);

  k_select<<<dim3(24), dim3(1024), 0, stream>>>(sc3, sc4, sc5, dl3, dl4, dl5, out);
}

// Round 7
// 2931.872 us; speedup vs baseline: 11.8133x; 1.3295x over previous
//
#include <hip/hip_runtime.h>
#include <math.h>
#include <stdint.h>

#define BBOX_CLAMP 4.135166556742356f
#define SQH 0.70710678118654752f
#define SQ2 1.41421356237309515f

__device__ __forceinline__ unsigned okey(float f){
  unsigned u = __float_as_uint(f);
  return (u & 0x80000000u) ? ~u : (u | 0x80000000u);
}

// ---------------- one-time weight transpose: wT[(cin*9+k)*256 + co] ----------------
__global__ void k_wtrans(const float* __restrict__ w, float* __restrict__ wT){
  const int ck = blockIdx.x;      // cin*9+k  (0..2303)
  const int co = threadIdx.x;     // 0..255
  wT[ck*256 + co] = w[co*2304 + ck];
}

// ---------------- fused stem conv3x3+bias+relu + obj/box 1x1 heads ----------------
// Row-stationary conv, fully inline. CRITICAL: plain __launch_bounds__(256) with
// NO min-waves argument — any min-waves value here force-spills the accumulator
// (r2/r3/r4: WRITE_SIZE tens of GB). r6 ledger: VGPR 164 / LDS 34 KB gave only
// 1 block/CU resident; this round slims LDS to ~9 KB (channel-quartered head
// buffer) and halves acc (TH=4) to raise residency.
// Per-output fmaf order: cin asc -> kh asc -> kw asc; head channels 0..255 asc.
template<int TH>
__global__ __launch_bounds__(256) void k_stem(
    const float* __restrict__ feat,   // [8][256][H][W]
    const float* __restrict__ wT,     // [2304][256]
    const float* __restrict__ bstem,  // [256]
    const float* __restrict__ wobj,   // [3][256]
    const float* __restrict__ bobj,   // [3]
    const float* __restrict__ wbox,   // [12][256]
    const float* __restrict__ bbox,   // [12]
    float* __restrict__ scores,       // [8][H*W*3]
    float* __restrict__ deltas,       // [8][H*W*12]
    const int H, const int W)
{
  __shared__ __align__(16) float in_a[TH+2][12];
  __shared__ __align__(16) float in_b[TH+2][12];
  __shared__ float x_q[32][65];      // one channel-quarter of 32 pixels

  const int tx0 = blockIdx.x*8, ty0 = blockIdx.y*TH;
  const int b = blockIdx.z;
  const int co = threadIdx.x;
  const size_t HW = (size_t)H*W;
  const float* fb = feat + (size_t)b*256*HW;

  constexpr int LC = (TH+2)*10;
  const int lty = co/10, ltx = co - (co/10)*10;
  const bool lactive = (co < LC);
  const int gy = ty0-1+lty, gx = tx0-1+ltx;
  const bool inb = lactive && (gy>=0 && gy<H && gx>=0 && gx<W);
  const float* gsrc = fb + ((size_t)(inb?gy:0)*W + (size_t)(inb?gx:0));

  float acc[TH*8];
#pragma unroll
  for (int i=0;i<TH*8;++i) acc[i]=0.f;

  // preload cin 0: tile -> in_a, weights -> wa
  if (lactive) in_a[lty][ltx] = inb ? *gsrc : 0.f;
  float wa[9], wb[9];
  const float* wp = wT + co;
#pragma unroll
  for (int k=0;k<9;++k) wa[k] = wp[k*256];
  wp += 9*256;                       // now points at cin 1 weights
  const float* gn = gsrc + HW;       // next tile value (cin 1)
  __syncthreads();

#define UPD(PY, KH, WR) { \
  _Pragma("unroll") \
  for (int px=0; px<8; ++px){ \
    float s = acc[(PY)*8+px]; \
    s = fmaf(rw[px+0], WR[(KH)*3+0], s); \
    s = fmaf(rw[px+1], WR[(KH)*3+1], s); \
    s = fmaf(rw[px+2], WR[(KH)*3+2], s); \
    acc[(PY)*8+px] = s; \
  } }

#define DOROW(R, TILE, WR) \
  if constexpr ((R) < TH+2) { \
    const float4 q0 = *reinterpret_cast<const float4*>(&TILE[(R)][0]); \
    const float4 q1 = *reinterpret_cast<const float4*>(&TILE[(R)][4]); \
    const float4 q2 = *reinterpret_cast<const float4*>(&TILE[(R)][8]); \
    const float rw[12] = {q0.x,q0.y,q0.z,q0.w, q1.x,q1.y,q1.z,q1.w, q2.x,q2.y,q2.z,q2.w}; \
    if constexpr ((R) <= TH-1)               UPD((R),   0, WR) \
    if constexpr ((R) >= 1 && (R)-1 <= TH-1) UPD((R)-1, 1, WR) \
    if constexpr ((R) >= 2)                  UPD((R)-2, 2, WR) \
  }

#define DOROWS(TILE, WR) \
  DOROW(0,TILE,WR) DOROW(1,TILE,WR) DOROW(2,TILE,WR) DOROW(3,TILE,WR) DOROW(4,TILE,WR) \
  DOROW(5,TILE,WR) DOROW(6,TILE,WR) DOROW(7,TILE,WR) DOROW(8,TILE,WR) DOROW(9,TILE,WR)

  for (int it=0; it<128; ++it){
    // ---- cin 2it (tile in_a, weights wa); prefetch cin 2it+1 ----
    float pv = 0.f;
    if (inb) pv = gn[0];
#pragma unroll
    for (int k=0;k<9;++k) wb[k] = wp[k*256];

    DOROWS(in_a, wa)

    if (lactive) in_b[lty][ltx] = pv;   // write-late
    __syncthreads();

    // ---- cin 2it+1 (tile in_b, weights wb); prefetch cin 2it+2 ----
    pv = 0.f;
    if (it < 127){
      if (inb) pv = gn[HW];
#pragma unroll
      for (int k=0;k<9;++k) wa[k] = wp[(9+k)*256];
    }

    DOROWS(in_b, wb)

    if (it < 127){
      if (lactive) in_a[lty][ltx] = pv;
    }
    __syncthreads();

    gn += 2*HW;
    wp += 18*256;
  }
#undef DOROWS
#undef DOROW
#undef UPD

  // bias + relu
  const float bs = bstem[co];
#pragma unroll
  for (int i=0;i<TH*8;++i) acc[i] = fmaxf(acc[i]+bs, 0.f);

  // heads: 32-pixel groups x channel quarters through a small LDS buffer.
  // Accumulation: cq=0..3 asc, c asc within -> channels 0..255 asc (bit-identical).
  const int p_loc = co & 31;
  const int g = co >> 5;                 // 0..7
  const int oc0 = g*2, oc1 = g*2+1;      // oc in [0,16), 15 unused
  const float* wh0 = (oc0<3) ? (wobj + oc0*256) : (wbox + (oc0-3)*256);
  const float* wh1 = (oc1<3) ? (wobj + oc1*256) : ((oc1<15) ? (wbox + (oc1-3)*256) : wbox);
  const float bias0 = (oc0<3) ? bobj[oc0] : bbox[oc0-3];
  const float bias1 = (oc1<3) ? bobj[oc1] : ((oc1<15) ? bbox[oc1-3] : 0.f);
  const int myq = co >> 6;               // this thread's channel quarter
  const int cql = co & 63;               // channel index within quarter

  constexpr int NH = (TH*8)/32;
#pragma unroll
  for (int half=0; half<NH; ++half){
    float s0 = 0.f, s1 = 0.f;
#pragma unroll
    for (int cq=0; cq<4; ++cq){
      __syncthreads();                   // x_q free from previous chunk's readers
      if (myq == cq){
#pragma unroll
        for (int i=0;i<32;++i) x_q[i][cql] = acc[half*32 + i];
      }
      __syncthreads();
      const float* w0q = wh0 + cq*64;
      const float* w1q = wh1 + cq*64;
#pragma unroll
      for (int c=0;c<64;++c){
        const float xv = x_q[p_loc][c];
        s0 = fmaf(xv, w0q[c], s0);
        s1 = fmaf(xv, w1q[c], s1);
      }
    }
    s0 += bias0; s1 += bias1;
    const int p  = half*32 + p_loc;
    const int py = p>>3, px = p&7;
    const int hh = ty0+py, ww = tx0+px;
    const size_t loc = (size_t)hh*W + ww;
    if (oc0 < 3) scores[b*HW*3 + loc*3 + oc0] = s0;
    else         deltas[b*HW*12 + loc*12 + (oc0-3)] = s0;
    if (oc1 < 3) scores[b*HW*3 + loc*3 + oc1] = s1;
    else if (oc1 < 15) deltas[b*HW*12 + loc*12 + (oc1-3)] = s1;
  }
}

// ---------------- per (level,image): top-400 -> decode -> NMS -> top-50 ----------------
__global__ __launch_bounds__(1024) void k_select(
    const float* __restrict__ sc3, const float* __restrict__ sc4, const float* __restrict__ sc5,
    const float* __restrict__ dl3, const float* __restrict__ dl4, const float* __restrict__ dl5,
    float* __restrict__ out)
{
  const int lvl = blockIdx.x >> 3;
  const int b   = blockIdx.x & 7;
  int N, W; float stride; const float* sc; const float* dl;
  if (lvl==0){ N=49152; W=128; stride=8.f;  sc=sc3; dl=dl3; }
  else if (lvl==1){ N=12288; W=64; stride=16.f; sc=sc4; dl=dl4; }
  else { N=3072; W=32; stride=32.f; sc=sc5; dl=dl5; }
  sc += (size_t)b*N;
  dl += (size_t)b*(size_t)(N/3)*12;

  __shared__ unsigned hist[256];
  __shared__ unsigned s_prefix;
  __shared__ int s_need;
  __shared__ int s_cntc;
  __shared__ unsigned long long cand[1024];
  __shared__ int tk[400];
  __shared__ float bx1[400], by1[400], bx2[400], by2[400], bar_[400];
  __shared__ unsigned long long mask[400][7];
  __shared__ int olist[50];

  const int t = threadIdx.x;

  // ---- radix-select: find key K of the 400th-largest score ----
  if (t==0){ s_prefix=0u; s_need=400; }
  for (int pass=0; pass<4; ++pass){
    const int shift = 24 - 8*pass;
    if (t<256) hist[t]=0u;
    __syncthreads();
    const unsigned pref = s_prefix;
    for (int i=t; i<N; i+=1024){
      const unsigned k = okey(sc[i]);
      if (pass==0 || (k >> (shift+8)) == pref)
        atomicAdd(&hist[(k>>shift)&255u], 1u);
    }
    __syncthreads();
    if (t==0){
      int need = s_need, cum=0, bsel=0;
      for (int bb=255; bb>=0; --bb){
        const int h = (int)hist[bb];
        if (cum + h >= need){ bsel=bb; break; }
        cum += h;
      }
      s_prefix = (pref<<8) | (unsigned)bsel;
      s_need = need - cum;
    }
    __syncthreads();
  }
  const unsigned K = s_prefix;

  // ---- compact candidates: all keys >= K (count >= 400 by construction) ----
  if (t==0) s_cntc = 0;
  cand[t] = 0ull;
  __syncthreads();
  for (int i=t; i<N; i+=1024){
    const unsigned k = okey(sc[i]);
    if (k >= K){
      const int pos = atomicAdd(&s_cntc, 1);
      if (pos < 1024)
        cand[pos] = ((unsigned long long)k<<32) | (unsigned long long)(0xFFFFFFFFu - (unsigned)i);
    }
  }
  __syncthreads();

  // ---- bitonic sort 1024 descending: (key desc, idx asc) ----
  for (int kk=2; kk<=1024; kk<<=1){
    for (int j=kk>>1; j>0; j>>=1){
      const int ixj = t ^ j;
      if (ixj > t){
        const unsigned long long a = cand[t], c = cand[ixj];
        const bool descending = ((t & kk) == 0);
        if ((a < c) == descending){ cand[t]=c; cand[ixj]=a; }
      }
      __syncthreads();
    }
  }

  // ---- decode top-400 boxes ----
  if (t < 400){
    const unsigned long long c = cand[t];
    const int gi = (int)(0xFFFFFFFFu - (unsigned)(c & 0xFFFFFFFFull));
    tk[t] = gi;
    const int loc = gi/3, a = gi - loc*3;
    const int hh = loc / W, ww = loc - hh*W;
    const float cx = (ww + 0.5f)*stride, cy = (hh + 0.5f)*stride;
    const float size = stride*8.f;
    const float sq = (a==0) ? SQH : ((a==1) ? 1.f : SQ2);
    const float hw_ = 0.5f*(size/sq);    // half width  (w = size/sqrt(r))
    const float hv_ = 0.5f*(size*sq);    // half height (h = size*sqrt(r))
    const float ax1 = cx - hw_, ax2 = cx + hw_;
    const float ay1 = cy - hv_, ay2 = cy + hv_;
    const float aw = ax2 - ax1, ah = ay2 - ay1;
    const float acx = ax1 + 0.5f*aw, acy = ay1 + 0.5f*ah;
    const float* dd = dl + (size_t)loc*12 + a*4;
    const float dx = dd[0], dy = dd[1];
    const float dw = fminf(fmaxf(dd[2], -BBOX_CLAMP), BBOX_CLAMP);
    const float dh = fminf(fmaxf(dd[3], -BBOX_CLAMP), BBOX_CLAMP);
    const float pcx = acx + dx*aw;
    const float pcy = acy + dy*ah;
    const float pw = aw*expf(dw);
    const float ph = ah*expf(dh);
    const float x1 = pcx - 0.5f*pw, y1 = pcy - 0.5f*ph;
    const float x2 = pcx + 0.5f*pw, y2 = pcy + 0.5f*ph;
    bx1[t]=x1; by1[t]=y1; bx2[t]=x2; by2[t]=y2;
    bar_[t] = fmaxf(x2-x1, 0.f)*fmaxf(y2-y1, 0.f);
  }
  __syncthreads();

  // ---- parallel 400x400 suppression bitmask ----
  for (int task=t; task<2800; task+=1024){
    const int i = task/7, w = task - (task/7)*7;
    unsigned long long m = 0ull;
    const float xi1=bx1[i], yi1=by1[i], xi2=bx2[i], yi2=by2[i], ai=bar_[i];
    const int j0 = w<<6;
    const int js = (j0 > i+1) ? j0 : (i+1);
    const int je = (j0+64 < 400) ? (j0+64) : 400;
    for (int j=js; j<je; ++j){
      const float ix1 = fmaxf(xi1, bx1[j]);
      const float iy1 = fmaxf(yi1, by1[j]);
      const float ix2 = fminf(xi2, bx2[j]);
      const float iy2 = fminf(yi2, by2[j]);
      const float inter = fmaxf(ix2-ix1, 0.f)*fmaxf(iy2-iy1, 0.f);
      const float iou = inter / fmaxf(ai + bar_[j] - inter, 1e-8f);
      if (iou > 0.6f) m |= (1ull << (j - j0));
    }
    mask[i][w] = m;
  }
  __syncthreads();

  // ---- serial suppression scan (word-parallel ANDs) + top-50 list ----
  if (t==0){
    unsigned long long keepw[7];
#pragma unroll
    for (int w=0;w<7;++w) keepw[w] = ~0ull;
    for (int i=0;i<400;++i){
      if ((keepw[i>>6] >> (i&63)) & 1ull){
#pragma unroll
        for (int w=0;w<7;++w) keepw[w] &= ~mask[i][w];
      }
    }
    int cnt=0;
    for (int i=0;i<400 && cnt<50;++i) if ( (keepw[i>>6]>>(i&63)) & 1ull) olist[cnt++]=i;
    for (int i=0;i<400 && cnt<50;++i) if (!((keepw[i>>6]>>(i&63)) & 1ull)) olist[cnt++]=i;
  }
  __syncthreads();

  if (t < 50){
    const int j = olist[t];
    float* o = out + (size_t)b*600 + (size_t)(lvl*50 + t)*4;
    o[0]=bx1[j]; o[1]=by1[j]; o[2]=bx2[j]; o[3]=by2[j];
  }
}

extern "C" void kernel_launch(void* const* d_in, const int* in_sizes, int n_in,
                              void* d_out, int out_size, void* d_ws, size_t ws_size,
                              hipStream_t stream) {
  (void)in_sizes; (void)n_in; (void)out_size; (void)ws_size;
  const float* p3     = (const float*)d_in[0];
  const float* p4     = (const float*)d_in[1];
  const float* p5     = (const float*)d_in[2];
  const float* w_stem = (const float*)d_in[3];
  const float* b_stem = (const float*)d_in[4];
  const float* w_obj  = (const float*)d_in[5];
  const float* b_obj  = (const float*)d_in[6];
  const float* w_box  = (const float*)d_in[7];
  const float* b_box  = (const float*)d_in[8];
  float* out = (float*)d_out;

  float* ws  = (float*)d_ws;
  float* wT  = ws;                    // 2304*256          = 589824
  float* sc3 = wT  + 589824;          // 8*128*128*3       = 393216
  float* sc4 = sc3 + 393216;          // 8*64*64*3         =  98304
  float* sc5 = sc4 + 98304;           // 8*32*32*3         =  24576
  float* dl3 = sc5 + 24576;           // 8*128*128*12      = 1572864
  float* dl4 = dl3 + 1572864;         // 8*64*64*12        = 393216
  float* dl5 = dl4 + 393216;          // 8*32*32*12        =  98304

  k_wtrans<<<dim3(2304), dim3(256), 0, stream>>>(w_stem, wT);

  k_stem<4><<<dim3(16,32,8), dim3(256), 0, stream>>>(p3, wT, b_stem, w_obj, b_obj, w_box, b_box, sc3, dl3, 128, 128);
  k_stem<4><<<dim3(8,16,8),  dim3(256), 0, stream>>>(p4, wT, b_stem, w_obj, b_obj, w_box, b_box, sc4, dl4, 64, 64);
  k_stem<4><<<dim3(4,8,8),   dim3(256), 0, stream>>>(p5, wT, b_stem, w_obj, b_obj, w_box, b_box, sc5, dl5, 32, 32);

  k_select<<<dim3(24), dim3(1024), 0, stream>>>(sc3, sc4, sc5, dl3, dl4, dl5, out);
}